// Round 11
// baseline (152.646 us; speedup 1.0000x reference)
//
#include <hip/hip_runtime.h>
#include <math.h>

#define SS 8192
#define HH 2048
#define NP 4
#define NBLK 1024
#define NTHR 512
#define NTILE 256

// Persistent device-global scratch (zero at module load; g_v2p re-zeroed by
// the softmax kernel every launch, stream-ordered). Counters are MONOTONE -
// never reset, so no launch-to-launch cleanup races:
//   g_tkt : 1024 grabs/launch  -> launch index = tkt / 1024
//   g_done: 256 bumps/launch   -> launch L complete when g_done == 256(L+1)
__device__ unsigned g_tkt  = 0;
__device__ unsigned g_done = 0;
__device__ float g_v2p[NP][HH];     // colsum partial slots
__device__ float g_sc[SS];          // raw scores

// ---- K1: colsum + rowdot merged via dynamic tickets (NO grid barrier, NO
// co-residency assumption). The first 256 blocks to EXECUTE grab the 256
// colsum tiles (ticket order = execution order), so progress never depends
// on dispatch order: spinners wait only on tiles owned by already-running
// blocks -> deadlock-free by construction. Late blocks see g_done at target
// and skip the spin entirely.
__global__ __launch_bounds__(NTHR) void fused1_kernel(
    const float* __restrict__ enc,
    const float* __restrict__ W,
    const float* __restrict__ w)
{
    const int b    = blockIdx.x;
    const int t    = threadIdx.x;
    const int wave = t >> 6;
    const int lane = t & 63;

    __shared__ float v2s[HH];       // 8 KB reduced v2
    __shared__ unsigned sh_tkt;

    if (t == 0)
        sh_tkt = __hip_atomic_fetch_add(&g_tkt, 1u, __ATOMIC_RELAXED,
                                        __HIP_MEMORY_SCOPE_AGENT);

    // enc prefetch issued IMMEDIATELY (1 row/wave, 8 independent float4):
    // the 64 MB enc stream overlaps colsum + spin below.
    const int row = b * 8 + wave;
    const float4* e = (const float4*)(enc + (size_t)row * HH);
    float4 er[8];
#pragma unroll
    for (int i = 0; i < 8; ++i)
        er[i] = e[lane + i * 64];

    __syncthreads();                        // sh_tkt visible
    const unsigned tkt    = sh_tkt;
    const unsigned tile   = tkt % NBLK;     // execution-order slot, 0..1023
    const unsigned target = (tkt / NBLK) * NTILE + NTILE;

    // First 256 running blocks: one colsum tile each (rows 8*tile.., all
    // 2048 cols, 512 thr x float4). atomicAdd into slot tile&3 -> 64-deep
    // chains/address (R5-proven contention level).
    if (tile < NTILE) {
        const int row0 = (int)tile * 8;
        const float4* wbase =
            (const float4*)(W + (size_t)row0 * (2 * HH) + HH) + t;
        float4 wv[8];
#pragma unroll
        for (int j = 0; j < 8; ++j)
            wv[j] = wbase[(size_t)j * ((2 * HH) / 4)];
        float4 acc = {0.f, 0.f, 0.f, 0.f};
#pragma unroll
        for (int j = 0; j < 8; ++j) {
            const float wj = w[row0 + j];   // block-uniform -> s_load
            acc.x += wj * wv[j].x; acc.y += wj * wv[j].y;
            acc.z += wj * wv[j].z; acc.w += wj * wv[j].w;
        }
        float* dst = &g_v2p[tile & (NP - 1)][t * 4];
        atomicAdd(dst + 0, acc.x);
        atomicAdd(dst + 1, acc.y);
        atomicAdd(dst + 2, acc.z);
        atomicAdd(dst + 3, acc.w);
    }

    // Pin er[] live in registers HERE (before the wait). Without this the
    // compiler sinks the enc loads below the spin (proven R7/R8/R9 via
    // VGPR_Count) and the overlap dies.
#pragma unroll
    for (int i = 0; i < 8; ++i)
        asm volatile("" :: "v"(er[i].x), "v"(er[i].y),
                           "v"(er[i].z), "v"(er[i].w));

    __syncthreads();   // drains every wave's atomics (vmcnt) before publish
    if (t == 0) {
        if (tile < NTILE)
            __hip_atomic_fetch_add(&g_done, 1u, __ATOMIC_RELAXED,
                                   __HIP_MEMORY_SCOPE_AGENT);
        while (__hip_atomic_load(&g_done, __ATOMIC_RELAXED,
                                 __HIP_MEMORY_SCOPE_AGENT) < target)
            __builtin_amdgcn_s_sleep(8);
    }
    __syncthreads();   // all 256 tiles complete & retired at coherent point

    // v2 slot-reduce -> LDS: 16 wave-coalesced coherent loads/thread
    // (R5-proven; R6 taught lane-strided coherent loads are fatal).
#pragma unroll
    for (int k = 0; k < 4; ++k) {
        const int c = t + k * 512;
        float s = 0.0f;
#pragma unroll
        for (int p = 0; p < NP; ++p)
            s += __hip_atomic_load(&g_v2p[p][c], __ATOMIC_RELAXED,
                                   __HIP_MEMORY_SCOPE_AGENT);
        v2s[c] = s;
    }
    __syncthreads();

    // rowdot: er already in registers; v2 fragment from LDS.
    const float4* v4 = (const float4*)v2s;
    float acc = 0.0f;
#pragma unroll
    for (int i = 0; i < 8; ++i) {
        const float4 vf = v4[lane + i * 64];
        acc += er[i].x * vf.x + er[i].y * vf.y
             + er[i].z * vf.z + er[i].w * vf.w;
    }
#pragma unroll
    for (int off = 32; off > 0; off >>= 1)
        acc += __shfl_down(acc, off);
    if (lane == 0) g_sc[row] = acc;         // plain store; kernel boundary
                                            // publishes it to K2
}

// ---- K2: softmax. grid 512, block 256. Every block redundantly reduces
// all 8192 scores (L2-resident after invalidate->refetch) and writes its
// own 16-element output slice. Blocks 0..7 re-zero g_v2p for the next
// launch (K2 never reads g_v2p -> no race; stream-ordered). ----
__global__ __launch_bounds__(256) void softmax_kernel(
    float* __restrict__ out)
{
    __shared__ float red[4];
    const int t    = threadIdx.x;
    const int lane = t & 63;
    const int wid  = t >> 6;
    const int b    = blockIdx.x;

    if (b < 8)                       // 8 blocks x 256 thr x float4 = 8192
        ((float4*)g_v2p)[b * 256 + t] = make_float4(0.f, 0.f, 0.f, 0.f);

    // 8 float4 loads = this thread's 32 scores (permutation-invariant
    // for max/sum, so the float4 regrouping is free accuracy-wise).
    float4 vq[8];
#pragma unroll
    for (int i = 0; i < 8; ++i)
        vq[i] = ((const float4*)g_sc)[t + i * 256];

    float m = -INFINITY;
#pragma unroll
    for (int i = 0; i < 8; ++i)
        m = fmaxf(fmaxf(fmaxf(m, vq[i].x), fmaxf(vq[i].y, vq[i].z)), vq[i].w);
#pragma unroll
    for (int off = 1; off < 64; off <<= 1)
        m = fmaxf(m, __shfl_xor(m, off));
    if (lane == 0) red[wid] = m;
    __syncthreads();
    m = fmaxf(fmaxf(red[0], red[1]), fmaxf(red[2], red[3]));

    float s = 0.0f;
#pragma unroll
    for (int i = 0; i < 8; ++i)
        s += __expf(vq[i].x - m) + __expf(vq[i].y - m)
           + __expf(vq[i].z - m) + __expf(vq[i].w - m);
#pragma unroll
    for (int off = 1; off < 64; off <<= 1)
        s += __shfl_xor(s, off);
    __syncthreads();                 // everyone done reading red (max)
    if (lane == 0) red[wid] = s;
    __syncthreads();
    const float inv = 1.0f / (red[0] + red[1] + red[2] + red[3]);

    if (t < 16) {
        const int e = b * 16 + t;
        out[e] = __expf(g_sc[e] - m) * inv;
    }
}

extern "C" void kernel_launch(void* const* d_in, const int* in_sizes, int n_in,
                              void* d_out, int out_size, void* d_ws, size_t ws_size,
                              hipStream_t stream) {
    const float* enc   = (const float*)d_in[0];  // (S,1,H) -> (S,H)
    // d_in[1] = hidden : constant score shift -> cancels in softmax
    const float* W_att = (const float*)d_in[2];  // (H, 2H)
    // d_in[3] = b_att  : constant shift -> cancels
    const float* w     = (const float*)d_in[4];  // (1, H)

    float* out = (float*)d_out;                  // 8192 floats (1,1,S)

    hipLaunchKernelGGL(fused1_kernel,  dim3(NBLK), dim3(NTHR), 0, stream,
                       enc, W_att, w);
    hipLaunchKernelGGL(softmax_kernel, dim3(512),  dim3(256),  0, stream,
                       out);
}